// Round 8
// baseline (18.113 us; speedup 1.0000x reference)
//
#include <hip/hip_runtime.h>
#include <hip/hip_bf16.h>

// AdjacencyMatchingLoss: B=8, NL=NQ=128, E=50000
// loss = -(1/B)*sum_b sum_{j,q} (M^T P_b)[j,q]*(P_b A^T)[j,q] / max(sum_w,1e-8)
// Round-8: round-7 structure (128 independent blocks = batch x j-half x edge
// shard, shard-linear M, MFMA dot) with:
//   - XCD-local decode: b = blk&7 -> all 16 blocks of batch b on one XCD L2
//   - single natural P slab (Pf) replaces conditional Pn staging
// 2 dispatches; plain-store partials (poison-proof); trivial final reduce.

typedef __attribute__((ext_vector_type(8))) short short8;
typedef __attribute__((ext_vector_type(16))) float f32x16;

constexpr int N = 128;
constexpr int BATCH = 8;
constexpr int NSH = 8;          // edge shards
constexpr int NBLK = 128;       // 8 b x 2 jh x 8 shards
// ws floats: [0..127] block partials, [128..135] per-shard weight sums

static __device__ __forceinline__ ushort bf16b(float x) {
    __hip_bfloat16 h = __float2bfloat16(x);   // RTNE
    return *reinterpret_cast<ushort*>(&h);
}

__global__ __launch_bounds__(512) void fused_kernel(
    const float* __restrict__ P, const int* __restrict__ A,
    const int* __restrict__ pairs, const float* __restrict__ w,
    int E, int epb, float* __restrict__ ws)
{
    __shared__ __align__(16) char arena[144 * 1024];
    char*  PtB = arena;                       // 32 KB: Pt[q][i] = P_b[i][q] bf16
    char*  AbB = arena + 32 * 1024;           // 32 KB: Ab[q][k] = (A[q][k]==1)
    char*  PfB = arena + 64 * 1024;           // 32 KB: Pf[i][k] = P_b[i][k] bf16
    char*  MtB = arena + 96 * 1024;           // 16 KB: Mt[jl][i] bf16 (shard M^T)
    float* Mf  = (float*)(arena + 112 * 1024);// 32 KB: Mf[i][jl] f32 scatter
    __shared__ float red[8];

    const int t   = threadIdx.x;
    const int blk = blockIdx.x;
    const int b   = blk & 7;          // batch -> XCD (wg%8 round-robin)
    const int jh  = (blk >> 3) & 1;   // j-half
    const int g   = blk >> 4;         // edge shard
    const int j0  = jh * 64;

    // ---- phase 0: zero the f32 M-slice ----
    #pragma unroll
    for (int r = 0; r < 4; ++r)
        ((float4*)Mf)[t + 512 * r] = float4{0.f, 0.f, 0.f, 0.f};
    __syncthreads();

    // ---- phase 1: stage P_b (natural + transposed), A; scatter shard edges ----
    const float4* P4 = (const float4*)(P + b * N * N);
    #pragma unroll
    for (int r = 0; r < 8; ++r) {
        int pos = t + 512 * r;
        float4 v = P4[pos];
        int i = pos >> 5;             // row of P_b
        int q4 = (pos & 31) * 4;      // col base
        ushort h0 = bf16b(v.x), h1 = bf16b(v.y), h2 = bf16b(v.z), h3 = bf16b(v.w);
        ushort4 hh = {h0, h1, h2, h3};
        *(ushort4*)(PfB + i * 256 + ((q4 * 2) ^ ((i & 15) << 4))) = hh;
        *(ushort*)(PtB + (q4 + 0) * 256 + ((i * 2) ^ (((q4 + 0) & 15) << 4))) = h0;
        *(ushort*)(PtB + (q4 + 1) * 256 + ((i * 2) ^ (((q4 + 1) & 15) << 4))) = h1;
        *(ushort*)(PtB + (q4 + 2) * 256 + ((i * 2) ^ (((q4 + 2) & 15) << 4))) = h2;
        *(ushort*)(PtB + (q4 + 3) * 256 + ((i * 2) ^ (((q4 + 3) & 15) << 4))) = h3;
    }
    const int4* A4 = (const int4*)A;
    #pragma unroll
    for (int r = 0; r < 8; ++r) {
        int pos = t + 512 * r;
        int4 av = A4[pos];
        int q = pos >> 5;
        int k4 = (pos & 31) * 4;
        ushort4 hh = {(ushort)(av.x == 1 ? 0x3F80 : 0), (ushort)(av.y == 1 ? 0x3F80 : 0),
                      (ushort)(av.z == 1 ? 0x3F80 : 0), (ushort)(av.w == 1 ? 0x3F80 : 0)};
        *(ushort4*)(AbB + q * 256 + ((k4 * 2) ^ ((q & 15) << 4))) = hh;
    }
    float wsum = 0.f;
    {
        const int base = g * epb;
        const int lim = min(base + epb, E);
        for (int e = base + t; e < lim; e += 512) {
            int2 ij = ((const int2*)pairs)[e];
            float we = w[e];
            wsum += we;                        // full-shard sum (used by blk&15==0)
            int jl = ij.y - j0;
            if ((unsigned)jl < 64u)
                atomicAdd(&Mf[ij.x * 64 + jl], we);
        }
    }
    __syncthreads();

    // ---- phase 2: convert Mf -> swizzled bf16 Mt[jl][i] ----
    #pragma unroll
    for (int r = 0; r < 4; ++r) {
        int pos = t + 512 * r;        // 2048: 128 i x 16 j4-groups
        int i = pos >> 4;
        int j4 = (pos & 15) * 4;
        float4 m = *(const float4*)&Mf[i * 64 + j4];
        *(ushort*)(MtB + (j4 + 0) * 256 + ((i * 2) ^ (((j4 + 0) & 15) << 4))) = bf16b(m.x);
        *(ushort*)(MtB + (j4 + 1) * 256 + ((i * 2) ^ (((j4 + 1) & 15) << 4))) = bf16b(m.y);
        *(ushort*)(MtB + (j4 + 2) * 256 + ((i * 2) ^ (((j4 + 2) & 15) << 4))) = bf16b(m.z);
        *(ushort*)(MtB + (j4 + 3) * 256 + ((i * 2) ^ (((j4 + 3) & 15) << 4))) = bf16b(m.w);
    }
    __syncthreads();

    // ---- phase 3: U = Mt x Pt, W = Pf-slice x Ab (32x32x16 MFMA); dot accs ----
    const int wv = t >> 6;
    const int lane = t & 63;
    const int qt = wv & 3;
    const int jt = wv >> 2;                   // 0..1 (j-half local)
    const int arow = jt * 32 + (lane & 31);   // local j row (Mt; Pf at +j0)
    const int brow = qt * 32 + (lane & 31);   // rows of Pt / Ab (q)
    const int koff = (lane >> 5) * 16;        // byte offset of lane's k-chunk

    f32x16 accU, accW;
    #pragma unroll
    for (int r = 0; r < 16; ++r) { accU[r] = 0.f; accW[r] = 0.f; }

    const int axor = (arow & 15) << 4;        // (j0+arow)&15 == arow&15 (j0%16==0)
    const int bxor = (brow & 15) << 4;
    const char* aUb = MtB + arow * 256;
    const char* aWb = PfB + (j0 + arow) * 256;
    const char* bUb = PtB + brow * 256;
    const char* bWb = AbB + brow * 256;
    #pragma unroll
    for (int ks = 0; ks < 8; ++ks) {
        int kb = ks * 32 + koff;
        short8 aU = *(const short8*)(aUb + (kb ^ axor));
        short8 bU = *(const short8*)(bUb + (kb ^ bxor));
        short8 aW = *(const short8*)(aWb + (kb ^ axor));
        short8 bW = *(const short8*)(bWb + (kb ^ bxor));
        accU = __builtin_amdgcn_mfma_f32_32x32x16_bf16(aU, bU, accU, 0, 0, 0);
        accW = __builtin_amdgcn_mfma_f32_32x32x16_bf16(aW, bW, accW, 0, 0, 0);
    }

    float s = 0.f;
    #pragma unroll
    for (int r = 0; r < 16; ++r) s += accU[r] * accW[r];
    #pragma unroll
    for (int off = 32; off > 0; off >>= 1)
        s += __shfl_down(s, off, 64);
    if (lane == 0) red[wv] = s;
    __syncthreads();
    if (t == 0) {
        float bs = 0.f;
        #pragma unroll
        for (int i = 0; i < 8; ++i) bs += red[i];
        ws[blk] = bs;                          // plain store, poison-proof
    }

    // one block per shard (b==0, jh==0) publishes the full-shard weight sum
    if ((blk & 15) == 0) {
        __syncthreads();
        #pragma unroll
        for (int off = 32; off > 0; off >>= 1)
            wsum += __shfl_down(wsum, off, 64);
        if ((t & 63) == 0) red[t >> 6] = wsum;
        __syncthreads();
        if (t == 0) {
            float sw = 0.f;
            #pragma unroll
            for (int i = 0; i < 8; ++i) sw += red[i];
            ws[NBLK + g] = sw;                 // plain store
        }
    }
}

__global__ __launch_bounds__(128) void final_kernel(
    const float* __restrict__ ws, float* __restrict__ out)
{
    __shared__ float red[2];
    const int t = threadIdx.x;
    float s = ws[t];                           // 128 block partials
    #pragma unroll
    for (int off = 32; off > 0; off >>= 1)
        s += __shfl_down(s, off, 64);
    if ((t & 63) == 0) red[t >> 6] = s;
    __syncthreads();
    if (t == 0) {
        float tot = red[0] + red[1];
        float tw = 0.f;
        #pragma unroll
        for (int i = 0; i < NSH; ++i) tw += ws[NBLK + i];
        out[0] = -(tot / (float)BATCH) / fmaxf(tw, 1e-8f);
    }
}

extern "C" void kernel_launch(void* const* d_in, const int* in_sizes, int n_in,
                              void* d_out, int out_size, void* d_ws, size_t ws_size,
                              hipStream_t stream)
{
    const float* P     = (const float*)d_in[0];
    const int*   A     = (const int*)d_in[1];
    const int*   pairs = (const int*)d_in[2];
    const float* w     = (const float*)d_in[3];
    const int    E     = in_sizes[3];
    const int    epb   = (E + NSH - 1) / NSH;

    float* ws = (float*)d_ws;

    fused_kernel<<<dim3(NBLK), 512, 0, stream>>>(P, A, pairs, w, E, epb, ws);
    final_kernel<<<dim3(1), 128, 0, stream>>>(ws, (float*)d_out);
}